// Round 4
// baseline (320.792 us; speedup 1.0000x reference)
//
#include <hip/hip_runtime.h>
#include <math.h>

// out[b] = log( sum_{kk in [0,65536)} w[kk>>8] * W0[kk, x0[b]] * W1[kk, x1[b]] )
//
// v5: pure split-k (256 blocks = 256 latent k, 1 block/CU, w block-uniform),
// ZERO-LDS, ZERO-BARRIER main loop. Each wave owns a 64(c0) x 128(c1) output
// sub-tile and reads its fragment elements DIRECTLY from global memory as
// f32 (lane-contiguous 64B chunks), converts to bf16 in-register (same RNE
// as before -> bit-identical results), and MFMAs. Within-block re-reads
// (A x2, B x4) are served by L1/L2 (~1.5 MB/CU, overlapped under the 0.5
// MB/CU unique HBM stream = 134 MB total, read exactly once). No staging
// bursts, no vmcnt(0) drains: 8 independent waves keep ~100 loads in
// flight continuously -> HBM duty cycle ~100%, BW-bound.
// Epilogue (unchanged, verified): gather the 1024 needed (x0,x1) cells via
// a 64-row LDS quarter-tile; finish: coalesced row-sum + log.

#define KCHUNK 256
#define BK     32
#define NITER  (KCHUNK / BK)   // 8

typedef float  f32x4  __attribute__((ext_vector_type(4)));
typedef short  bf16x8 __attribute__((ext_vector_type(8)));

static __device__ __forceinline__ short f2bf(float f) {
    // RNE fp32 -> bf16 (inputs are positive probabilities; no NaN/Inf)
    unsigned u = __builtin_bit_cast(unsigned, f);
    u += 0x7fffu + ((u >> 16) & 1u);
    return (short)(u >> 16);
}

static __device__ __forceinline__ bf16x8 pack8(const float* f) {
    bf16x8 r;
#pragma unroll
    for (int j = 0; j < 8; ++j) r[j] = f2bf(f[j]);
    return r;
}

__global__ __launch_bounds__(512, 2) void gemm_gather_kernel(
    const int* __restrict__ x, const float* __restrict__ W,
    const float* __restrict__ wsum, float* __restrict__ G)
{
    extern __shared__ char smem[];
    float* __restrict__ Sg = (float*)smem;         // [64][256] epilogue only

    const int  split = blockIdx.x;                 // 0..255 == latent k
    const long kbase = (long)split * KCHUNK;
    const float* __restrict__ Ag = W + kbase * 256;              // W0 chunk
    const float* __restrict__ Bg = W + 16777216 + kbase * 256;   // W1 chunk

    const int t    = threadIdx.x;
    const int lane = t & 63;
    const int wv   = t >> 6;             // wave 0..7
    const int wc0  = (wv & 3) * 64;      // 4 wave-tiles along c0
    const int wc1  = (wv >> 2) * 128;    // 2 along c1
    const int ml   = lane & 15;
    const int qd   = lane >> 4;

    // hoist the batch-index loads: latency rides out under the K-loop
    const int b0 = t, b1 = t + 512;
    const int2 xa = ((const int2*)x)[b0];
    const int2 xb = ((const int2*)x)[b1];

    f32x4 acc[4][8];
#pragma unroll
    for (int i = 0; i < 4; ++i)
#pragma unroll
        for (int j = 0; j < 8; ++j) acc[i][j] = (f32x4){0.f, 0.f, 0.f, 0.f};

    // fragment element (verified mapping): afr[mi][j] = A[k = qd*8+j][c = wc0+mi*16+ml]
    for (int it = 0; it < NITER; ++it) {
        const float* __restrict__ pA = Ag + ((long)it * BK + qd * 8) * 256;
        const float* __restrict__ pB = Bg + ((long)it * BK + qd * 8) * 256;

        float a[4][8];
#pragma unroll
        for (int mi = 0; mi < 4; ++mi)
#pragma unroll
            for (int j = 0; j < 8; ++j)
                a[mi][j] = pA[(long)j * 256 + wc0 + mi * 16 + ml];

        float b[4][8];
#pragma unroll
        for (int ni = 0; ni < 4; ++ni)
#pragma unroll
            for (int j = 0; j < 8; ++j)
                b[ni][j] = pB[(long)j * 256 + wc1 + ni * 16 + ml];

        bf16x8 afr[4];
#pragma unroll
        for (int mi = 0; mi < 4; ++mi) afr[mi] = pack8(a[mi]);

#pragma unroll
        for (int ni = 0; ni < 4; ++ni) {
            const bf16x8 bfr = pack8(b[ni]);
#pragma unroll
            for (int mi = 0; mi < 4; ++mi)
                acc[mi][ni] = __builtin_amdgcn_mfma_f32_16x16x32_bf16(
                    afr[mi], bfr, acc[mi][ni], 0, 0, 0);
        }

        // second c1-half: reuse b[] registers
#pragma unroll
        for (int ni = 0; ni < 4; ++ni)
#pragma unroll
            for (int j = 0; j < 8; ++j)
                b[ni][j] = pB[(long)j * 256 + wc1 + (ni + 4) * 16 + ml];

#pragma unroll
        for (int ni = 0; ni < 4; ++ni) {
            const bf16x8 bfr = pack8(b[ni]);
#pragma unroll
            for (int mi = 0; mi < 4; ++mi)
                acc[mi][ni + 4] = __builtin_amdgcn_mfma_f32_16x16x32_bf16(
                    afr[mi], bfr, acc[mi][ni + 4], 0, 0, 0);
        }
    }

    // Epilogue: gather the 1024 needed cells of this block's 256x256 tile.
    // C/D layout: col = lane&15, row = (lane>>4)*4 + reg (harness-verified).
    // 4 rounds of 64 c0-rows; wave group with wc0==q*64 dumps into LDS.
    float v0 = 0.f, v1 = 0.f;
#pragma unroll
    for (int q = 0; q < 4; ++q) {
        __syncthreads();                    // prior round's reads complete
        if (wc0 == q * 64) {
#pragma unroll
            for (int mi = 0; mi < 4; ++mi)
#pragma unroll
                for (int ni = 0; ni < 8; ++ni)
#pragma unroll
                    for (int r = 0; r < 4; ++r)
                        Sg[(mi * 16 + qd * 4 + r) * 256 + wc1 + ni * 16 + ml] =
                            acc[mi][ni][r];
        }
        __syncthreads();
        if ((xa.x >> 6) == q) v0 = Sg[(xa.x & 63) * 256 + xa.y];
        if ((xb.x >> 6) == q) v1 = Sg[(xb.x & 63) * 256 + xb.y];
    }
    const float w = wsum[split];            // block-uniform, applied once in f32
    G[(long)b0 * 256 + split] = v0 * w;
    G[(long)b1 * 256 + split] = v1 * w;
}

// One wave per b: contiguous 1 KB row of G, float4 loads, shuffle-reduce, log.
__global__ __launch_bounds__(256) void finish_kernel(
    const float* __restrict__ G, float* __restrict__ out)
{
    const int b    = blockIdx.x * 4 + (threadIdx.x >> 6);
    const int lane = threadIdx.x & 63;
    const float4 g = ((const float4*)(G + (long)b * 256))[lane];
    float v = (g.x + g.y) + (g.z + g.w);
#pragma unroll
    for (int off = 32; off > 0; off >>= 1) v += __shfl_down(v, off);
    if (lane == 0) out[b] = logf(v);
}

extern "C" void kernel_launch(void* const* d_in, const int* in_sizes, int n_in,
                              void* d_out, int out_size, void* d_ws, size_t ws_size,
                              hipStream_t stream)
{
    const int*   x    = (const int*)d_in[0];     // [1024,2] int32
    const float* W    = (const float*)d_in[1];   // [2,256,256,256] fp32
    const float* wsum = (const float*)d_in[2];   // [256] fp32
    float* G   = (float*)d_ws;                   // [1024][256] f32 = 1 MB
    float* out = (float*)d_out;                  // [1024] fp32

    gemm_gather_kernel<<<dim3(256), 512, 65536, stream>>>(x, W, wsum, G);
    finish_kernel<<<dim3(256), 256, 0, stream>>>(G, out);
}

// Round 5
// 224.653 us; speedup vs baseline: 1.4279x; 1.4279x over previous
//
#include <hip/hip_runtime.h>
#include <math.h>

// out[b] = log( sum_{kk in [0,65536)} w[kk>>8] * W0[kk, x0[b]] * W1[kk, x1[b]] )
//
// v6: pure split-k (256 blocks = 256 latent k, 1 block/CU, w block-uniform)
// with global_load_lds DMA staging + EXPLICIT counted vmcnt (T3/T4).
// Loads have no VGPR destination, so the compiler cannot insert its own
// vmcnt drains: we issue tile it+1's 8x16B gll per thread, then wait
// `s_waitcnt vmcnt(8)` for tile it (the 8 newest stay in flight across
// the whole compute phase) -> HBM queue never empties, transfer-bound
// steady state. LDS holds raw f32 ([k][c] linear, as in global); the
// f32->bf16 RNE convert moves to fragment-read time (bit-identical values
// to v2). 128 KB static LDS = 2 x (A 32KB + B 32KB). Epilogue (verified)
// gathers the 1024 needed (x0,x1) cells via a 64-row LDS quarter-tile
// aliased over the staging buffers; finish: coalesced row-sum + log.

#define KCHUNK 256
#define BK     32
#define NITER  (KCHUNK / BK)   // 8

typedef float  f32x4  __attribute__((ext_vector_type(4)));
typedef short  bf16x8 __attribute__((ext_vector_type(8)));

static __device__ __forceinline__ short f2bf(float f) {
    // RNE fp32 -> bf16 (inputs are positive probabilities; no NaN/Inf)
    unsigned u = __builtin_bit_cast(unsigned, f);
    u += 0x7fffu + ((u >> 16) & 1u);
    return (short)(u >> 16);
}

static __device__ __forceinline__ bf16x8 pack8(const float* f) {
    bf16x8 r;
#pragma unroll
    for (int j = 0; j < 8; ++j) r[j] = f2bf(f[j]);
    return r;
}

// async 16B global -> LDS (DMA, no VGPR dest). LDS dest is wave-uniform
// base; HW adds lane*16. Tracked by vmcnt only.
static __device__ __forceinline__ void gll16(const float* g, float* l) {
    __builtin_amdgcn_global_load_lds(
        (const __attribute__((address_space(1))) unsigned int*)g,
        (__attribute__((address_space(3))) unsigned int*)l,
        16, 0, 0);
}

__global__ __launch_bounds__(512, 2) void gemm_gather_kernel(
    const int* __restrict__ x, const float* __restrict__ W,
    const float* __restrict__ wsum, float* __restrict__ G)
{
    __shared__ __align__(16) float smem[32768];    // 128 KB: 2 x (A 8192f + B 8192f)

    const int  split = blockIdx.x;                 // 0..255 == latent k
    const long kbase = (long)split * KCHUNK;
    const float* __restrict__ Ag = W + kbase * 256;              // W0 chunk
    const float* __restrict__ Bg = W + 16777216 + kbase * 256;   // W1 chunk

    const int t    = threadIdx.x;
    const int lane = t & 63;
    const int wv   = t >> 6;             // wave 0..7
    const int wc0  = (wv & 3) * 64;      // 4 wave-tiles along c0
    const int wc1  = (wv >> 2) * 128;    // 2 along c1
    const int ml   = lane & 15;
    const int qd   = lane >> 4;

    // batch indices: load now, force complete so the K-loop's vmcnt counts
    // see ONLY our gll ops (loads cannot sink past a memory-clobber asm)
    const int b0 = t, b1 = t + 512;
    const int2 xa = ((const int2*)x)[b0];
    const int2 xb = ((const int2*)x)[b1];
    asm volatile("s_waitcnt vmcnt(0)" ::: "memory");

    f32x4 acc[4][8];
#pragma unroll
    for (int i = 0; i < 4; ++i)
#pragma unroll
        for (int j = 0; j < 8; ++j) acc[i][j] = (f32x4){0.f, 0.f, 0.f, 0.f};

    // tile `tl` of A/B = 32 rows x 256 c = 8192 floats, CONTIGUOUS in global.
    // Per thread: 4 gll x A + 4 gll x B = 8 x 16B. LDS layout == global ([k][c]).
#define STAGE(tl, base_)                                                       \
    do {                                                                       \
        const float* ga_ = Ag + (long)(tl) * 8192;                             \
        const float* gb_ = Bg + (long)(tl) * 8192;                             \
        _Pragma("unroll")                                                      \
        for (int r = 0; r < 4; ++r) {                                          \
            const int off = r * 2048 + wv * 256;      /* floats, wave-uniform */ \
            gll16(ga_ + off + lane * 4, smem + (base_) + off);                 \
            gll16(gb_ + off + lane * 4, smem + (base_) + 8192 + off);          \
        }                                                                      \
    } while (0)

    // fragment (verified mapping): element [k = qd*8+j][c = w*+i*16+ml]
#define COMPUTE(base_)                                                         \
    do {                                                                       \
        const float* As_ = smem + (base_);                                     \
        const float* Bs_ = smem + (base_) + 8192;                              \
        bf16x8 afr[4];                                                         \
        _Pragma("unroll")                                                      \
        for (int mi = 0; mi < 4; ++mi) {                                       \
            float tv[8];                                                       \
            _Pragma("unroll")                                                  \
            for (int j = 0; j < 8; ++j)                                        \
                tv[j] = As_[(qd * 8 + j) * 256 + wc0 + mi * 16 + ml];          \
            afr[mi] = pack8(tv);                                               \
        }                                                                      \
        _Pragma("unroll")                                                      \
        for (int ni = 0; ni < 8; ++ni) {                                       \
            float tv[8];                                                       \
            _Pragma("unroll")                                                  \
            for (int j = 0; j < 8; ++j)                                        \
                tv[j] = Bs_[(qd * 8 + j) * 256 + wc1 + ni * 16 + ml];          \
            const bf16x8 bfr = pack8(tv);                                      \
            _Pragma("unroll")                                                  \
            for (int mi = 0; mi < 4; ++mi)                                     \
                acc[mi][ni] = __builtin_amdgcn_mfma_f32_16x16x32_bf16(         \
                    afr[mi], bfr, acc[mi][ni], 0, 0, 0);                       \
        }                                                                      \
    } while (0)

    STAGE(0, 0);
#pragma unroll
    for (int it = 0; it < NITER; ++it) {
        const int base = (it & 1) ? 16384 : 0;
        if (it + 1 < NITER) {
            STAGE(it + 1, base ^ 16384);       // 8 newest loads: next tile
            asm volatile("s_waitcnt vmcnt(8)" ::: "memory");  // tile it landed
        } else {
            asm volatile("s_waitcnt vmcnt(0)" ::: "memory");
        }
        __builtin_amdgcn_s_barrier();          // all waves' tile-it DMA landed
        asm volatile("" ::: "memory");         // no ds_read hoist above barrier
        COMPUTE(base);
        asm volatile("s_waitcnt lgkmcnt(0)" ::: "memory");
        __builtin_amdgcn_s_barrier();          // all reads of `base` done
        asm volatile("" ::: "memory");         // next STAGE can't hoist above
    }
#undef STAGE
#undef COMPUTE

    // Epilogue: gather the 1024 needed cells of this block's 256x256 tile.
    // C/D layout: col = lane&15, row = (lane>>4)*4 + reg (harness-verified).
    // 4 rounds of 64 c0-rows; wave group with wc0==q*64 dumps into LDS.
    float* __restrict__ Sg = smem;             // [64][256] alias, 64 KB
    float v0 = 0.f, v1 = 0.f;
#pragma unroll
    for (int q = 0; q < 4; ++q) {
        __syncthreads();                    // prior round's reads complete
        if (wc0 == q * 64) {
#pragma unroll
            for (int mi = 0; mi < 4; ++mi)
#pragma unroll
                for (int ni = 0; ni < 8; ++ni)
#pragma unroll
                    for (int r = 0; r < 4; ++r)
                        Sg[(mi * 16 + qd * 4 + r) * 256 + wc1 + ni * 16 + ml] =
                            acc[mi][ni][r];
        }
        __syncthreads();
        if ((xa.x >> 6) == q) v0 = Sg[(xa.x & 63) * 256 + xa.y];
        if ((xb.x >> 6) == q) v1 = Sg[(xb.x & 63) * 256 + xb.y];
    }
    const float w = wsum[split];            // block-uniform, applied once in f32
    G[(long)b0 * 256 + split] = v0 * w;
    G[(long)b1 * 256 + split] = v1 * w;
}

// One wave per b: contiguous 1 KB row of G, float4 loads, shuffle-reduce, log.
__global__ __launch_bounds__(256) void finish_kernel(
    const float* __restrict__ G, float* __restrict__ out)
{
    const int b    = blockIdx.x * 4 + (threadIdx.x >> 6);
    const int lane = threadIdx.x & 63;
    const float4 g = ((const float4*)(G + (long)b * 256))[lane];
    float v = (g.x + g.y) + (g.z + g.w);
#pragma unroll
    for (int off = 32; off > 0; off >>= 1) v += __shfl_down(v, off);
    if (lane == 0) out[b] = logf(v);
}

extern "C" void kernel_launch(void* const* d_in, const int* in_sizes, int n_in,
                              void* d_out, int out_size, void* d_ws, size_t ws_size,
                              hipStream_t stream)
{
    const int*   x    = (const int*)d_in[0];     // [1024,2] int32
    const float* W    = (const float*)d_in[1];   // [2,256,256,256] fp32
    const float* wsum = (const float*)d_in[2];   // [256] fp32
    float* G   = (float*)d_ws;                   // [1024][256] f32 = 1 MB
    float* out = (float*)d_out;                  // [1024] fp32

    gemm_gather_kernel<<<dim3(256), 512, 0, stream>>>(x, W, wsum, G);
    finish_kernel<<<dim3(256), 256, 0, stream>>>(G, out);
}

// Round 7
// 200.738 us; speedup vs baseline: 1.5981x; 1.1191x over previous
//
#include <hip/hip_runtime.h>
#include <math.h>

// out[b] = log( sum_{kk in [0,65536)} w[kk>>8] * W0[kk, x0[b]] * W1[kk, x1[b]] )
//
// v7: restore occupancy-based overlap (the m97 mechanism) instead of
// intra-block pipelining (v3/v4/v6 all failed on the 128-VGPR acc wall).
// Tile 256(c0) x 128(c1), grid (2 c1-halves, 256 splits) = 512 blocks =
// 2 blocks/CU (acc[4][4]=64 VGPR, 32 KB LDS, __launch_bounds__(512,4)):
// while one block sits in its barrier/vmcnt(0) drain, the co-resident
// block's 8 waves compute -- transfer and compute overlap across blocks
// with the simple, verified 2-barrier schedule. A is read twice but the
// second read is largely L3-served (v5/v6 measured W half-L3-resident).
// Per-cell arithmetic identical to v2 (same f2bf RNE at stage time, same
// MFMA order, same single w multiply) -> absmax unchanged.
// Epilogue: each block gathers the b's whose x1 lies in its c1-half via a
// 64x128 LDS quarter-tile (G cells written exactly once); finish:
// coalesced row-sum + log.

#define KCHUNK 256
#define BK     32
#define NITER  (KCHUNK / BK)   // 8
#define LDSS   40              // shorts per c-row: 32 k + 8 pad = 80 B

typedef float  f32x4  __attribute__((ext_vector_type(4)));
typedef short  bf16x8 __attribute__((ext_vector_type(8)));

static __device__ __forceinline__ short f2bf(float f) {
    // RNE fp32 -> bf16 (inputs are positive probabilities; no NaN/Inf)
    unsigned u = __builtin_bit_cast(unsigned, f);
    u += 0x7fffu + ((u >> 16) & 1u);
    return (short)(u >> 16);
}

__global__ __launch_bounds__(512, 4) void gemm_gather_kernel(
    const int* __restrict__ x, const float* __restrict__ W,
    const float* __restrict__ wsum, float* __restrict__ G)
{
    extern __shared__ char smem[];
    short* __restrict__ As = (short*)smem;                      // [256][LDSS] 20.5 KB
    short* __restrict__ Bs = (short*)(smem + 256 * LDSS * 2);   // [128][LDSS] 10.25 KB
    float* __restrict__ Sg = (float*)smem;                      // [64][128] 32 KB alias

    const int  c1t   = blockIdx.x;                 // 0..1  c1 half
    const int  split = blockIdx.y;                 // 0..255 == latent k
    const long kbase = (long)split * KCHUNK;
    const float* __restrict__ Ag = W + kbase * 256;                          // W0 chunk
    const float* __restrict__ Bg = W + 16777216 + kbase * 256 + c1t * 128;   // W1 chunk+col

    const int t = threadIdx.x;
    // A staging: 64 c-quads x 8 k-rows, r=0..3  (4 float4 / thread)
    const int cqA = (t & 63) * 4;
    const int kqA = (t >> 6) * 4;
    // B staging: 32 c-quads x 16 k-rows, r=0..1 (2 float4 / thread)
    const int cqB = (t & 31) * 4;
    const int kqB = (t >> 5) * 2;

    const int lane = t & 63;
    const int wv   = t >> 6;             // wave 0..7
    const int wc0  = (wv & 3) * 64;      // 4 wave-tiles along c0 (256)
    const int wc1  = (wv >> 2) * 64;     // 2 along c1 (128)
    const int ml   = lane & 15;
    const int qd   = lane >> 4;

    // hoist batch indices: latency rides out under the K-loop
    const int b0 = t, b1 = t + 512;
    const int2 xa = ((const int2*)x)[b0];
    const int2 xb = ((const int2*)x)[b1];

    f32x4 acc[4][4];
#pragma unroll
    for (int i = 0; i < 4; ++i)
#pragma unroll
        for (int j = 0; j < 4; ++j) acc[i][j] = (f32x4){0.f, 0.f, 0.f, 0.f};

    for (int it = 0; it < NITER; ++it) {
        const long k0 = (long)it * BK;
        float4 a4[4], b4[2];
#pragma unroll
        for (int r = 0; r < 4; ++r)
            a4[r] = *(const float4*)(Ag + (k0 + kqA + r) * 256 + cqA);
#pragma unroll
        for (int r = 0; r < 2; ++r)
            b4[r] = *(const float4*)(Bg + (k0 + kqB + r) * 256 + cqB);
        __syncthreads();   // previous iteration's fragment reads complete
        const float* af = reinterpret_cast<const float*>(a4);
        const float* bf = reinterpret_cast<const float*>(b4);
#pragma unroll
        for (int j = 0; j < 4; ++j) {
            short4 av;
            av.x = f2bf(af[0 * 4 + j]);
            av.y = f2bf(af[1 * 4 + j]);
            av.z = f2bf(af[2 * 4 + j]);
            av.w = f2bf(af[3 * 4 + j]);
            *(short4*)&As[(cqA + j) * LDSS + kqA] = av;   // 8 B aligned
            short2 bv;
            bv.x = f2bf(bf[0 * 4 + j]);
            bv.y = f2bf(bf[1 * 4 + j]);
            *(short2*)&Bs[(cqB + j) * LDSS + kqB] = bv;   // 4 B aligned
        }
        __syncthreads();
        // fragment: lane holds [c = base+(lane&15)][k = (lane>>4)*8 + j]
        bf16x8 afr[4];
#pragma unroll
        for (int mi = 0; mi < 4; ++mi)
            afr[mi] = *(const bf16x8*)&As[(wc0 + mi * 16 + ml) * LDSS + qd * 8];
#pragma unroll
        for (int ni = 0; ni < 4; ++ni) {
            const bf16x8 bfr = *(const bf16x8*)&Bs[(wc1 + ni * 16 + ml) * LDSS + qd * 8];
#pragma unroll
            for (int mi = 0; mi < 4; ++mi)
                acc[mi][ni] = __builtin_amdgcn_mfma_f32_16x16x32_bf16(
                    afr[mi], bfr, acc[mi][ni], 0, 0, 0);
        }
    }

    // Epilogue: gather the needed (x0,x1) cells whose x1 lies in this c1-half.
    // C/D layout: col = lane&15, row = (lane>>4)*4 + reg (harness-verified).
    // 4 rounds of 64 c0-rows; waves with (wv&3)==q dump (both c1 sub-tiles).
    const bool own0 = (xa.y >> 7) == c1t;
    const bool own1 = (xb.y >> 7) == c1t;
    float v0 = 0.f, v1 = 0.f;
#pragma unroll
    for (int q = 0; q < 4; ++q) {
        __syncthreads();                    // prior round's reads complete
        if ((wv & 3) == q) {
#pragma unroll
            for (int mi = 0; mi < 4; ++mi)
#pragma unroll
                for (int ni = 0; ni < 4; ++ni)
#pragma unroll
                    for (int r = 0; r < 4; ++r)
                        Sg[(mi * 16 + qd * 4 + r) * 128 + wc1 + ni * 16 + ml] =
                            acc[mi][ni][r];
        }
        __syncthreads();
        if (own0 && (xa.x >> 6) == q) v0 = Sg[(xa.x & 63) * 128 + (xa.y & 127)];
        if (own1 && (xb.x >> 6) == q) v1 = Sg[(xb.x & 63) * 128 + (xb.y & 127)];
    }
    const float w = wsum[split];            // block-uniform, applied once in f32
    if (own0) G[(long)b0 * 256 + split] = v0 * w;
    if (own1) G[(long)b1 * 256 + split] = v1 * w;
}

// One wave per b: contiguous 1 KB row of G, float4 loads, shuffle-reduce, log.
__global__ __launch_bounds__(256) void finish_kernel(
    const float* __restrict__ G, float* __restrict__ out)
{
    const int b    = blockIdx.x * 4 + (threadIdx.x >> 6);
    const int lane = threadIdx.x & 63;
    const float4 g = ((const float4*)(G + (long)b * 256))[lane];
    float v = (g.x + g.y) + (g.z + g.w);
#pragma unroll
    for (int off = 32; off > 0; off >>= 1) v += __shfl_down(v, off);
    if (lane == 0) out[b] = logf(v);
}

extern "C" void kernel_launch(void* const* d_in, const int* in_sizes, int n_in,
                              void* d_out, int out_size, void* d_ws, size_t ws_size,
                              hipStream_t stream)
{
    const int*   x    = (const int*)d_in[0];     // [1024,2] int32
    const float* W    = (const float*)d_in[1];   // [2,256,256,256] fp32
    const float* wsum = (const float*)d_in[2];   // [256] fp32
    float* G   = (float*)d_ws;                   // [1024][256] f32 = 1 MB
    float* out = (float*)d_out;                  // [1024] fp32

    gemm_gather_kernel<<<dim3(2, 256), 512, 32768, stream>>>(x, W, wsum, G);
    finish_kernel<<<dim3(256), 256, 0, stream>>>(G, out);
}